// Round 11
// baseline (109.707 us; speedup 1.0000x reference)
//
#include <hip/hip_runtime.h>
#include <stdint.h>

#define NB 8
#define NN 1024
#define NF 64
#define NT 12
#define NK 3
#define NO 64
#define NQ 768      // O*T
#define KKC 3072    // NK*NN contraction

typedef __attribute__((ext_vector_type(8))) short bf16x8;
typedef __attribute__((ext_vector_type(4))) float f32x4;

typedef const unsigned int __attribute__((address_space(1)))* gas1_t;
typedef unsigned int __attribute__((address_space(3)))* las3_t;

__device__ __forceinline__ void gload_lds16(const void* g, void* l) {
  __builtin_amdgcn_global_load_lds((gas1_t)g, (las3_t)l, 16, 0, 0);
}

__device__ __forceinline__ unsigned short f2bf(float f) {
  union { float f; unsigned int u; } v; v.f = f;
  unsigned int u = v.u;
  unsigned int r = (u + 0x7FFFu + ((u >> 16) & 1u)) >> 16;
  return (unsigned short)r;
}

// ---------------------------------------------------------------------------
// K0: thetaT[k][o][f] = bf16(theta[k][f][o])
// ---------------------------------------------------------------------------
__global__ void k0_thetaT(const float* __restrict__ theta, unsigned short* __restrict__ thT) {
  int i = blockIdx.x * 256 + threadIdx.x;
  if (i >= NK * NO * NF) return;
  int f = i & 63, o = (i >> 6) & 63, k = i >> 12;
  thT[i] = f2bf(theta[(k * NF + f) * NO + o]);
}

// ---------------------------------------------------------------------------
// K1: A2[b][n][k*1024+m] = bf16(cheb[k][m][n]*att[b][m][n])
// grid (n0,m0) = 256 blocks; cheb tiles staged once, b-loop inside.
// ---------------------------------------------------------------------------
__global__ __launch_bounds__(256) void k1_A2(const float* __restrict__ cheb,
                                             const float* __restrict__ att,
                                             unsigned short* __restrict__ A2) {
  __shared__ float att_s[64][65];
  __shared__ float cheb_s[3][64][65];
  const int n0 = blockIdx.x * 64;
  const int m0 = blockIdx.y * 64;
  const int tid = threadIdx.x;
  const int r4 = tid >> 4;
  const int c  = tid & 15;

#pragma unroll
  for (int k = 0; k < NK; ++k)
#pragma unroll
    for (int p = 0; p < 4; ++p) {
      int r = r4 + p * 16;
      const float4 v = *(const float4*)(cheb + ((size_t)(k * NN + m0 + r)) * NN + n0 + c * 4);
      cheb_s[k][r][c * 4 + 0] = v.x; cheb_s[k][r][c * 4 + 1] = v.y;
      cheb_s[k][r][c * 4 + 2] = v.z; cheb_s[k][r][c * 4 + 3] = v.w;
    }

  for (int b = 0; b < NB; ++b) {
    __syncthreads();
#pragma unroll
    for (int p = 0; p < 4; ++p) {
      int r = r4 + p * 16;
      const float4 v = *(const float4*)(att + ((size_t)(b * NN + m0 + r)) * NN + n0 + c * 4);
      att_s[r][c * 4 + 0] = v.x; att_s[r][c * 4 + 1] = v.y;
      att_s[r][c * 4 + 2] = v.z; att_s[r][c * 4 + 3] = v.w;
    }
    __syncthreads();
    for (int k = 0; k < NK; ++k) {
#pragma unroll
      for (int p = 0; p < 8; ++p) {
        int e  = p * 256 + tid;
        int jn = e >> 5;
        int q  = e & 31;
        float f0 = att_s[2 * q][jn]     * cheb_s[k][2 * q][jn];
        float f1 = att_s[2 * q + 1][jn] * cheb_s[k][2 * q + 1][jn];
        unsigned int pk = (unsigned int)f2bf(f0) | ((unsigned int)f2bf(f1) << 16);
        size_t el = ((size_t)(b * NN + n0 + jn)) * KKC + k * NN + m0 + 2 * q;
        *(unsigned int*)(A2 + el) = pk;
      }
    }
  }
}

// ---------------------------------------------------------------------------
// K23 (fused k2+k3): Y[b][(o,t)][k*1024+m] = sum_f x[b,m,f,t] * theta[k,f,o]
// grid (mc 64, b 8) = 512 blocks, 256 thr (4 waves, 3 t's each).
// ---------------------------------------------------------------------------
__global__ __launch_bounds__(256) void k23_Y(const float* __restrict__ x,
                                             const unsigned short* __restrict__ thT,
                                             unsigned short* __restrict__ Y) {
  __shared__ unsigned short Xs[12 * 16 * 64];   // 24 KB, t-plane stride 2048 B
  __shared__ unsigned short Ts[3 * 64 * 64];    // 24 KB, k-plane stride 8192 B
  const int mc = blockIdx.x;
  const int b  = blockIdx.y;
  const int tid = threadIdx.x;
  const int w = tid >> 6, l = tid & 63;
  const int lrow = l & 15, lk = l >> 4;

  const float* xb = x + ((size_t)(b * NN + mc * 16)) * (NF * NT);
#pragma unroll
  for (int u0 = 0; u0 < 2; ++u0) {
    const int u  = u0 * 256 + tid;       // 0..511
    const int m  = u >> 5;               // 0..15
    const int fp = u & 31;               // f-pair
    const float* src = xb + ((size_t)m * NF + fp * 2) * NT;
    float v[24];
#pragma unroll
    for (int i = 0; i < 6; ++i)
      *(float4*)(v + i * 4) = *(const float4*)(src + i * 4);
#pragma unroll
    for (int t = 0; t < 12; ++t) {
      unsigned int pk = (unsigned int)f2bf(v[t]) | ((unsigned int)f2bf(v[t + 12]) << 16);
      const int byte = (t * 2048 + m * 128 + fp * 4) ^ ((m & 7) << 4);
      *(unsigned int*)((char*)Xs + byte) = pk;
    }
  }
#pragma unroll
  for (int u0 = 0; u0 < 6; ++u0) {
    const int u  = u0 * 256 + tid;       // 0..1535
    const int k  = u >> 9;
    const int o  = (u >> 3) & 63;
    const int f8 = u & 7;
    bf16x8 val = *(const bf16x8*)(thT + (size_t)u * 8);
    const int byte = (k * 8192 + o * 128 + f8 * 16) ^ ((o & 7) << 4);
    *(bf16x8*)((char*)Ts + byte) = val;
  }
  __syncthreads();

#pragma unroll
  for (int ti = 0; ti < 3; ++ti) {
    const int t = w * 3 + ti;
    bf16x8 af[2];
#pragma unroll
    for (int kss = 0; kss < 2; ++kss) {
      const int byte = (t * 2048 + lrow * 128 + kss * 64 + lk * 16) ^ ((lrow & 7) << 4);
      af[kss] = *(const bf16x8*)((const char*)Xs + byte);
    }
    for (int k = 0; k < NK; ++k) {
      f32x4 acc[4] = {};
#pragma unroll
      for (int kss = 0; kss < 2; ++kss) {
#pragma unroll
        for (int oj = 0; oj < 4; ++oj) {
          const int row = oj * 16 + lrow;
          const int byte = (k * 8192 + row * 128 + kss * 64 + lk * 16) ^ ((row & 7) << 4);
          bf16x8 bb = *(const bf16x8*)((const char*)Ts + byte);
          acc[oj] = __builtin_amdgcn_mfma_f32_16x16x32_bf16(af[kss], bb, acc[oj], 0, 0, 0);
        }
      }
#pragma unroll
      for (int oj = 0; oj < 4; ++oj) {
        const int o  = oj * 16 + lrow;
        const int mg = mc * 16 + lk * 4;
        uint2 u;
        u.x = (unsigned int)f2bf(acc[oj][0]) | ((unsigned int)f2bf(acc[oj][1]) << 16);
        u.y = (unsigned int)f2bf(acc[oj][2]) | ((unsigned int)f2bf(acc[oj][3]) << 16);
        size_t el = ((size_t)(b * NQ + o * NT + t)) * KKC + k * NN + mg;
        *(uint2*)(void*)(Y + el) = u;
      }
    }
  }
}

// ---------------------------------------------------------------------------
// K4: out[b][n][q] = relu( A2[b] @ Y[b]^T ), 64x64 tile, BK=64.
// Empirical law from r3/r7/r9/r10: time ≈ staged_bytes / (5.9 TB/s ×
// blocks_per_CU) — i.e. time ∝ (BM+BN) at constant per-block delivery.
// 64x64 minimizes BM+BN (128) and grid 16x12x8 = 1536 = exactly 6/CU
// raises aggregate delivery toward the ~34 TB/s L2 ceiling.
// LDS 16 KB x 6 = 96 KB; acc 2x2; 24 waves/CU. Same proven 2-barrier
// single-buffer loop + both-sides XOR swizzle. XCD chunk = 192 = one b.
// ---------------------------------------------------------------------------
__global__ __launch_bounds__(256) void k4_main(const unsigned short* __restrict__ A2,
                                               const unsigned short* __restrict__ Y,
                                               float* __restrict__ out) {
  __shared__ unsigned short Asl[64 * 64];   // 8 KB
  __shared__ unsigned short Bsl[64 * 64];   // 8 KB
  const int tid = threadIdx.x;
  const int w = tid >> 6, l = tid & 63;
  const int lrow = l & 15, lk = l >> 4;
  const int wm = w >> 1, wq = w & 1;

  // bijective XCD-chunk swizzle (1536 % 8 == 0); 192 blocks = one b per XCD
  const int lin = (blockIdx.x & 7) * 192 + (blockIdx.x >> 3);
  const int b   = lin / 192;
  const int rem = lin % 192;
  const int bn  = rem / 12;      // 0..15, 64-row n-tile
  const int bq  = rem % 12;      // 0..11, 64-col q-tile

  const unsigned short* Abase = A2 + ((size_t)(b * NN + bn * 64)) * KKC;
  const unsigned short* Bbase = Y  + ((size_t)(b * NQ + bq * 64)) * KKC;

  f32x4 acc[2][2] = {};

  for (int kt = 0; kt < KKC / 64; ++kt) {
    const int kb = kt * 64;
    // A: 512 16B-units, 2/thread
#pragma unroll
    for (int it = 0; it < 2; ++it) {
      const int idx = it * 256 + tid;
      const int r   = idx >> 3;
      const int c16 = (idx & 7) ^ (r & 7);
      gload_lds16(Abase + (size_t)r * KKC + kb + c16 * 8, Asl + (size_t)idx * 8);
    }
    // B: 512 16B-units, 2/thread
#pragma unroll
    for (int it = 0; it < 2; ++it) {
      const int idx = it * 256 + tid;
      const int r   = idx >> 3;
      const int c16 = (idx & 7) ^ (r & 7);
      gload_lds16(Bbase + (size_t)r * KKC + kb + c16 * 8, Bsl + (size_t)idx * 8);
    }
    __syncthreads();
#pragma unroll
    for (int kss = 0; kss < 2; ++kss) {
      bf16x8 af[2], bfr[2];
#pragma unroll
      for (int mi = 0; mi < 2; ++mi) {
        const int row = wm * 32 + mi * 16 + lrow;
        const int sw = (row * 128 + kss * 64 + lk * 16) ^ ((row & 7) << 4);
        af[mi] = *(const bf16x8*)((const char*)Asl + sw);
      }
#pragma unroll
      for (int nj = 0; nj < 2; ++nj) {
        const int row = wq * 32 + nj * 16 + lrow;
        const int sw = (row * 128 + kss * 64 + lk * 16) ^ ((row & 7) << 4);
        bfr[nj] = *(const bf16x8*)((const char*)Bsl + sw);
      }
#pragma unroll
      for (int mi = 0; mi < 2; ++mi)
#pragma unroll
        for (int nj = 0; nj < 2; ++nj)
          acc[mi][nj] = __builtin_amdgcn_mfma_f32_16x16x32_bf16(af[mi], bfr[nj], acc[mi][nj], 0, 0, 0);
    }
    __syncthreads();
  }

  const int nb0 = bn * 64 + wm * 32;
  const int qb0 = bq * 64 + wq * 32;
#pragma unroll
  for (int mi = 0; mi < 2; ++mi) {
#pragma unroll
    for (int nj = 0; nj < 2; ++nj) {
      const int q = qb0 + nj * 16 + lrow;
#pragma unroll
      for (int j = 0; j < 4; ++j) {
        const int n = nb0 + mi * 16 + lk * 4 + j;
        float v = acc[mi][nj][j];
        out[((size_t)(b * NN + n)) * NQ + q] = v > 0.f ? v : 0.f;
      }
    }
  }
}

// ---------------------------------------------------------------------------
extern "C" void kernel_launch(void* const* d_in, const int* in_sizes, int n_in,
                              void* d_out, int out_size, void* d_ws, size_t ws_size,
                              hipStream_t stream) {
  const float* x     = (const float*)d_in[0];   // (B,N,F,T)
  const float* att   = (const float*)d_in[1];   // (B,N,N)
  const float* cheb  = (const float*)d_in[2];   // (K,N,N)
  const float* theta = (const float*)d_in[3];   // (K,F,O)
  float* out = (float*)d_out;

  char* ws = (char*)d_ws;
  unsigned short* A2  = (unsigned short*)(ws);                 // 50,331,648 B
  unsigned short* Y   = (unsigned short*)(ws + 50331648);      // 37,748,736 B
  unsigned short* thT = (unsigned short*)(ws + 88080384);      //     24,576 B

  k0_thetaT<<<48, 256, 0, stream>>>(theta, thT);
  k23_Y<<<dim3(64, 8), 256, 0, stream>>>(x, thT, Y);
  k1_A2<<<dim3(16, 16), 256, 0, stream>>>(cheb, att, A2);
  k4_main<<<1536, 256, 0, stream>>>(A2, Y, out);
}

// Round 12
// 108.552 us; speedup vs baseline: 1.0106x; 1.0106x over previous
//
#include <hip/hip_runtime.h>
#include <stdint.h>

#define NB 8
#define NN 1024
#define NF 64
#define NT 12
#define NK 3
#define NO 64
#define NQ 768      // O*T
#define KKC 3072    // NK*NN contraction

typedef __attribute__((ext_vector_type(8))) short bf16x8;
typedef __attribute__((ext_vector_type(4))) float f32x4;

typedef const unsigned int __attribute__((address_space(1)))* gas1_t;
typedef unsigned int __attribute__((address_space(3)))* las3_t;

__device__ __forceinline__ void gload_lds16(const void* g, void* l) {
  __builtin_amdgcn_global_load_lds((gas1_t)g, (las3_t)l, 16, 0, 0);
}

__device__ __forceinline__ unsigned short f2bf(float f) {
  union { float f; unsigned int u; } v; v.f = f;
  unsigned int u = v.u;
  unsigned int r = (u + 0x7FFFu + ((u >> 16) & 1u)) >> 16;
  return (unsigned short)r;
}

// ---------------------------------------------------------------------------
// K0: thetaT[k][o][f] = bf16(theta[k][f][o])
// ---------------------------------------------------------------------------
__global__ void k0_thetaT(const float* __restrict__ theta, unsigned short* __restrict__ thT) {
  int i = blockIdx.x * 256 + threadIdx.x;
  if (i >= NK * NO * NF) return;
  int f = i & 63, o = (i >> 6) & 63, k = i >> 12;
  thT[i] = f2bf(theta[(k * NF + f) * NO + o]);
}

// ---------------------------------------------------------------------------
// K1: A2[b][n][k*1024+m] = bf16(cheb[k][m][n]*att[b][m][n])
// grid (n0,m0) = 256 blocks; cheb tiles staged once, b-loop inside.
// ---------------------------------------------------------------------------
__global__ __launch_bounds__(256) void k1_A2(const float* __restrict__ cheb,
                                             const float* __restrict__ att,
                                             unsigned short* __restrict__ A2) {
  __shared__ float att_s[64][65];
  __shared__ float cheb_s[3][64][65];
  const int n0 = blockIdx.x * 64;
  const int m0 = blockIdx.y * 64;
  const int tid = threadIdx.x;
  const int r4 = tid >> 4;
  const int c  = tid & 15;

#pragma unroll
  for (int k = 0; k < NK; ++k)
#pragma unroll
    for (int p = 0; p < 4; ++p) {
      int r = r4 + p * 16;
      const float4 v = *(const float4*)(cheb + ((size_t)(k * NN + m0 + r)) * NN + n0 + c * 4);
      cheb_s[k][r][c * 4 + 0] = v.x; cheb_s[k][r][c * 4 + 1] = v.y;
      cheb_s[k][r][c * 4 + 2] = v.z; cheb_s[k][r][c * 4 + 3] = v.w;
    }

  for (int b = 0; b < NB; ++b) {
    __syncthreads();
#pragma unroll
    for (int p = 0; p < 4; ++p) {
      int r = r4 + p * 16;
      const float4 v = *(const float4*)(att + ((size_t)(b * NN + m0 + r)) * NN + n0 + c * 4);
      att_s[r][c * 4 + 0] = v.x; att_s[r][c * 4 + 1] = v.y;
      att_s[r][c * 4 + 2] = v.z; att_s[r][c * 4 + 3] = v.w;
    }
    __syncthreads();
    for (int k = 0; k < NK; ++k) {
#pragma unroll
      for (int p = 0; p < 8; ++p) {
        int e  = p * 256 + tid;
        int jn = e >> 5;
        int q  = e & 31;
        float f0 = att_s[2 * q][jn]     * cheb_s[k][2 * q][jn];
        float f1 = att_s[2 * q + 1][jn] * cheb_s[k][2 * q + 1][jn];
        unsigned int pk = (unsigned int)f2bf(f0) | ((unsigned int)f2bf(f1) << 16);
        size_t el = ((size_t)(b * NN + n0 + jn)) * KKC + k * NN + m0 + 2 * q;
        *(unsigned int*)(A2 + el) = pk;
      }
    }
  }
}

// ---------------------------------------------------------------------------
// K23 (fused k2+k3): Y[b][(o,t)][k*1024+m] = sum_f x[b,m,f,t] * theta[k,f,o]
// grid (mc 64, b 8) = 512 blocks, 256 thr (4 waves, 3 t's each).
// ---------------------------------------------------------------------------
__global__ __launch_bounds__(256) void k23_Y(const float* __restrict__ x,
                                             const unsigned short* __restrict__ thT,
                                             unsigned short* __restrict__ Y) {
  __shared__ unsigned short Xs[12 * 16 * 64];   // 24 KB, t-plane stride 2048 B
  __shared__ unsigned short Ts[3 * 64 * 64];    // 24 KB, k-plane stride 8192 B
  const int mc = blockIdx.x;
  const int b  = blockIdx.y;
  const int tid = threadIdx.x;
  const int w = tid >> 6, l = tid & 63;
  const int lrow = l & 15, lk = l >> 4;

  const float* xb = x + ((size_t)(b * NN + mc * 16)) * (NF * NT);
#pragma unroll
  for (int u0 = 0; u0 < 2; ++u0) {
    const int u  = u0 * 256 + tid;       // 0..511
    const int m  = u >> 5;               // 0..15
    const int fp = u & 31;               // f-pair
    const float* src = xb + ((size_t)m * NF + fp * 2) * NT;
    float v[24];
#pragma unroll
    for (int i = 0; i < 6; ++i)
      *(float4*)(v + i * 4) = *(const float4*)(src + i * 4);
#pragma unroll
    for (int t = 0; t < 12; ++t) {
      unsigned int pk = (unsigned int)f2bf(v[t]) | ((unsigned int)f2bf(v[t + 12]) << 16);
      const int byte = (t * 2048 + m * 128 + fp * 4) ^ ((m & 7) << 4);
      *(unsigned int*)((char*)Xs + byte) = pk;
    }
  }
#pragma unroll
  for (int u0 = 0; u0 < 6; ++u0) {
    const int u  = u0 * 256 + tid;       // 0..1535
    const int k  = u >> 9;
    const int o  = (u >> 3) & 63;
    const int f8 = u & 7;
    bf16x8 val = *(const bf16x8*)(thT + (size_t)u * 8);
    const int byte = (k * 8192 + o * 128 + f8 * 16) ^ ((o & 7) << 4);
    *(bf16x8*)((char*)Ts + byte) = val;
  }
  __syncthreads();

#pragma unroll
  for (int ti = 0; ti < 3; ++ti) {
    const int t = w * 3 + ti;
    bf16x8 af[2];
#pragma unroll
    for (int kss = 0; kss < 2; ++kss) {
      const int byte = (t * 2048 + lrow * 128 + kss * 64 + lk * 16) ^ ((lrow & 7) << 4);
      af[kss] = *(const bf16x8*)((const char*)Xs + byte);
    }
    for (int k = 0; k < NK; ++k) {
      f32x4 acc[4] = {};
#pragma unroll
      for (int kss = 0; kss < 2; ++kss) {
#pragma unroll
        for (int oj = 0; oj < 4; ++oj) {
          const int row = oj * 16 + lrow;
          const int byte = (k * 8192 + row * 128 + kss * 64 + lk * 16) ^ ((row & 7) << 4);
          bf16x8 bb = *(const bf16x8*)((const char*)Ts + byte);
          acc[oj] = __builtin_amdgcn_mfma_f32_16x16x32_bf16(af[kss], bb, acc[oj], 0, 0, 0);
        }
      }
#pragma unroll
      for (int oj = 0; oj < 4; ++oj) {
        const int o  = oj * 16 + lrow;
        const int mg = mc * 16 + lk * 4;
        uint2 u;
        u.x = (unsigned int)f2bf(acc[oj][0]) | ((unsigned int)f2bf(acc[oj][1]) << 16);
        u.y = (unsigned int)f2bf(acc[oj][2]) | ((unsigned int)f2bf(acc[oj][3]) << 16);
        size_t el = ((size_t)(b * NQ + o * NT + t)) * KKC + k * NN + mg;
        *(uint2*)(void*)(Y + el) = u;
      }
    }
  }
}

// ---------------------------------------------------------------------------
// K4: out[b][n][q] = relu( A2[b] @ Y[b]^T ), 64x64 tile, BK=64.
// Empirical law from r3/r7/r9/r10: time ≈ staged_bytes / (5.9 TB/s ×
// blocks_per_CU) — i.e. time ∝ (BM+BN) at constant per-block delivery.
// 64x64 minimizes BM+BN (128) and grid 16x12x8 = 1536 = exactly 6/CU
// raises aggregate delivery toward the ~34 TB/s L2 ceiling.
// LDS 16 KB x 6 = 96 KB; acc 2x2; 24 waves/CU. Same proven 2-barrier
// single-buffer loop + both-sides XOR swizzle. XCD chunk = 192 = one b.
// ---------------------------------------------------------------------------
__global__ __launch_bounds__(256) void k4_main(const unsigned short* __restrict__ A2,
                                               const unsigned short* __restrict__ Y,
                                               float* __restrict__ out) {
  __shared__ unsigned short Asl[64 * 64];   // 8 KB
  __shared__ unsigned short Bsl[64 * 64];   // 8 KB
  const int tid = threadIdx.x;
  const int w = tid >> 6, l = tid & 63;
  const int lrow = l & 15, lk = l >> 4;
  const int wm = w >> 1, wq = w & 1;

  // bijective XCD-chunk swizzle (1536 % 8 == 0); 192 blocks = one b per XCD
  const int lin = (blockIdx.x & 7) * 192 + (blockIdx.x >> 3);
  const int b   = lin / 192;
  const int rem = lin % 192;
  const int bn  = rem / 12;      // 0..15, 64-row n-tile
  const int bq  = rem % 12;      // 0..11, 64-col q-tile

  const unsigned short* Abase = A2 + ((size_t)(b * NN + bn * 64)) * KKC;
  const unsigned short* Bbase = Y  + ((size_t)(b * NQ + bq * 64)) * KKC;

  f32x4 acc[2][2] = {};

  for (int kt = 0; kt < KKC / 64; ++kt) {
    const int kb = kt * 64;
    // A: 512 16B-units, 2/thread
#pragma unroll
    for (int it = 0; it < 2; ++it) {
      const int idx = it * 256 + tid;
      const int r   = idx >> 3;
      const int c16 = (idx & 7) ^ (r & 7);
      gload_lds16(Abase + (size_t)r * KKC + kb + c16 * 8, Asl + (size_t)idx * 8);
    }
    // B: 512 16B-units, 2/thread
#pragma unroll
    for (int it = 0; it < 2; ++it) {
      const int idx = it * 256 + tid;
      const int r   = idx >> 3;
      const int c16 = (idx & 7) ^ (r & 7);
      gload_lds16(Bbase + (size_t)r * KKC + kb + c16 * 8, Bsl + (size_t)idx * 8);
    }
    __syncthreads();
#pragma unroll
    for (int kss = 0; kss < 2; ++kss) {
      bf16x8 af[2], bfr[2];
#pragma unroll
      for (int mi = 0; mi < 2; ++mi) {
        const int row = wm * 32 + mi * 16 + lrow;
        const int sw = (row * 128 + kss * 64 + lk * 16) ^ ((row & 7) << 4);
        af[mi] = *(const bf16x8*)((const char*)Asl + sw);
      }
#pragma unroll
      for (int nj = 0; nj < 2; ++nj) {
        const int row = wq * 32 + nj * 16 + lrow;
        const int sw = (row * 128 + kss * 64 + lk * 16) ^ ((row & 7) << 4);
        bfr[nj] = *(const bf16x8*)((const char*)Bsl + sw);
      }
#pragma unroll
      for (int mi = 0; mi < 2; ++mi)
#pragma unroll
        for (int nj = 0; nj < 2; ++nj)
          acc[mi][nj] = __builtin_amdgcn_mfma_f32_16x16x32_bf16(af[mi], bfr[nj], acc[mi][nj], 0, 0, 0);
    }
    __syncthreads();
  }

  const int nb0 = bn * 64 + wm * 32;
  const int qb0 = bq * 64 + wq * 32;
#pragma unroll
  for (int mi = 0; mi < 2; ++mi) {
#pragma unroll
    for (int nj = 0; nj < 2; ++nj) {
      const int q = qb0 + nj * 16 + lrow;
#pragma unroll
      for (int j = 0; j < 4; ++j) {
        const int n = nb0 + mi * 16 + lk * 4 + j;
        float v = acc[mi][nj][j];
        out[((size_t)(b * NN + n)) * NQ + q] = v > 0.f ? v : 0.f;
      }
    }
  }
}

// ---------------------------------------------------------------------------
extern "C" void kernel_launch(void* const* d_in, const int* in_sizes, int n_in,
                              void* d_out, int out_size, void* d_ws, size_t ws_size,
                              hipStream_t stream) {
  const float* x     = (const float*)d_in[0];   // (B,N,F,T)
  const float* att   = (const float*)d_in[1];   // (B,N,N)
  const float* cheb  = (const float*)d_in[2];   // (K,N,N)
  const float* theta = (const float*)d_in[3];   // (K,F,O)
  float* out = (float*)d_out;

  char* ws = (char*)d_ws;
  unsigned short* A2  = (unsigned short*)(ws);                 // 50,331,648 B
  unsigned short* Y   = (unsigned short*)(ws + 50331648);      // 37,748,736 B
  unsigned short* thT = (unsigned short*)(ws + 88080384);      //     24,576 B

  k0_thetaT<<<48, 256, 0, stream>>>(theta, thT);
  k23_Y<<<dim3(64, 8), 256, 0, stream>>>(x, thT, Y);
  k1_A2<<<dim3(16, 16), 256, 0, stream>>>(cheb, att, A2);
  k4_main<<<1536, 256, 0, stream>>>(A2, Y, out);
}

// Round 13
// 94.631 us; speedup vs baseline: 1.1593x; 1.1471x over previous
//
#include <hip/hip_runtime.h>
#include <stdint.h>

#define NB 8
#define NN 1024
#define NF 64
#define NT 12
#define NK 3
#define NO 64
#define NQ 768      // O*T
#define KKC 3072    // NK*NN contraction

typedef __attribute__((ext_vector_type(8))) short bf16x8;
typedef __attribute__((ext_vector_type(4))) float f32x4;

typedef const unsigned int __attribute__((address_space(1)))* gas1_t;
typedef unsigned int __attribute__((address_space(3)))* las3_t;

__device__ __forceinline__ void gload_lds16(const void* g, void* l) {
  __builtin_amdgcn_global_load_lds((gas1_t)g, (las3_t)l, 16, 0, 0);
}

__device__ __forceinline__ unsigned short f2bf(float f) {
  union { float f; unsigned int u; } v; v.f = f;
  unsigned int u = v.u;
  unsigned int r = (u + 0x7FFFu + ((u >> 16) & 1u)) >> 16;
  return (unsigned short)r;
}

// ---------------------------------------------------------------------------
// K0: thetaT[k][o][f] = bf16(theta[k][f][o])
// ---------------------------------------------------------------------------
__global__ void k0_thetaT(const float* __restrict__ theta, unsigned short* __restrict__ thT) {
  int i = blockIdx.x * 256 + threadIdx.x;
  if (i >= NK * NO * NF) return;
  int f = i & 63, o = (i >> 6) & 63, k = i >> 12;
  thT[i] = f2bf(theta[(k * NF + f) * NO + o]);
}

// ---------------------------------------------------------------------------
// K123 (fused k23 + k1): 768 blocks, whole-block role split.
//   blocks [0,512):   Y[b][(o,t)][k*1024+m] = sum_f x[b,m,f,t]*theta[k,f,o]
//   blocks [512,768): A2[b][n][k*1024+m]    = bf16(cheb[k,m,n]*att[b,m,n])
// Both are BW-bound and independent — fusing fills the machine (768 blocks
// vs 512/256 alone) and removes a launch gap. LDS = union (66.5 KB, 2/CU).
// ---------------------------------------------------------------------------
__global__ __launch_bounds__(256) void k123(const float* __restrict__ x,
                                            const unsigned short* __restrict__ thT,
                                            unsigned short* __restrict__ Y,
                                            const float* __restrict__ cheb,
                                            const float* __restrict__ att,
                                            unsigned short* __restrict__ A2) {
  __shared__ alignas(16) char smem[66560];
  const int bid = blockIdx.x;
  const int tid = threadIdx.x;

  if (bid < 512) {
    // ---------------- k23 role: build Y ----------------
    unsigned short* Xs = (unsigned short*)smem;            // 24 KB, t-plane 2048 B
    unsigned short* Ts = (unsigned short*)(smem + 24576);  // 24 KB, k-plane 8192 B
    const int mc = bid & 63;
    const int b  = bid >> 6;
    const int w = tid >> 6, l = tid & 63;
    const int lrow = l & 15, lk = l >> 4;

    const float* xb = x + ((size_t)(b * NN + mc * 16)) * (NF * NT);
#pragma unroll
    for (int u0 = 0; u0 < 2; ++u0) {
      const int u  = u0 * 256 + tid;       // 0..511
      const int m  = u >> 5;               // 0..15
      const int fp = u & 31;               // f-pair
      const float* src = xb + ((size_t)m * NF + fp * 2) * NT;
      float v[24];
#pragma unroll
      for (int i = 0; i < 6; ++i)
        *(float4*)(v + i * 4) = *(const float4*)(src + i * 4);
#pragma unroll
      for (int t = 0; t < 12; ++t) {
        unsigned int pk = (unsigned int)f2bf(v[t]) | ((unsigned int)f2bf(v[t + 12]) << 16);
        const int byte = (t * 2048 + m * 128 + fp * 4) ^ ((m & 7) << 4);
        *(unsigned int*)((char*)Xs + byte) = pk;
      }
    }
#pragma unroll
    for (int u0 = 0; u0 < 6; ++u0) {
      const int u  = u0 * 256 + tid;       // 0..1535
      const int k  = u >> 9;
      const int o  = (u >> 3) & 63;
      const int f8 = u & 7;
      bf16x8 val = *(const bf16x8*)(thT + (size_t)u * 8);
      const int byte = (k * 8192 + o * 128 + f8 * 16) ^ ((o & 7) << 4);
      *(bf16x8*)((char*)Ts + byte) = val;
    }
    __syncthreads();

#pragma unroll
    for (int ti = 0; ti < 3; ++ti) {
      const int t = w * 3 + ti;
      bf16x8 af[2];
#pragma unroll
      for (int kss = 0; kss < 2; ++kss) {
        const int byte = (t * 2048 + lrow * 128 + kss * 64 + lk * 16) ^ ((lrow & 7) << 4);
        af[kss] = *(const bf16x8*)((const char*)Xs + byte);
      }
      for (int k = 0; k < NK; ++k) {
        f32x4 acc[4] = {};
#pragma unroll
        for (int kss = 0; kss < 2; ++kss) {
#pragma unroll
          for (int oj = 0; oj < 4; ++oj) {
            const int row = oj * 16 + lrow;
            const int byte = (k * 8192 + row * 128 + kss * 64 + lk * 16) ^ ((row & 7) << 4);
            bf16x8 bb = *(const bf16x8*)((const char*)Ts + byte);
            acc[oj] = __builtin_amdgcn_mfma_f32_16x16x32_bf16(af[kss], bb, acc[oj], 0, 0, 0);
          }
        }
#pragma unroll
        for (int oj = 0; oj < 4; ++oj) {
          const int o  = oj * 16 + lrow;
          const int mg = mc * 16 + lk * 4;
          uint2 u;
          u.x = (unsigned int)f2bf(acc[oj][0]) | ((unsigned int)f2bf(acc[oj][1]) << 16);
          u.y = (unsigned int)f2bf(acc[oj][2]) | ((unsigned int)f2bf(acc[oj][3]) << 16);
          size_t el = ((size_t)(b * NQ + o * NT + t)) * KKC + k * NN + mg;
          *(uint2*)(void*)(Y + el) = u;
        }
      }
    }
  } else {
    // ---------------- k1 role: build A2 ----------------
    float (*att_s)[65]      = (float(*)[65])smem;                    // 16.6 KB
    float (*cheb_s)[64][65] = (float(*)[64][65])(smem + 16640);      // 49.9 KB
    const int bid2 = bid - 512;          // 0..255
    const int n0 = (bid2 >> 4) * 64;
    const int m0 = (bid2 & 15) * 64;
    const int r4 = tid >> 4;
    const int c  = tid & 15;

#pragma unroll
    for (int k = 0; k < NK; ++k)
#pragma unroll
      for (int p = 0; p < 4; ++p) {
        int r = r4 + p * 16;
        const float4 v = *(const float4*)(cheb + ((size_t)(k * NN + m0 + r)) * NN + n0 + c * 4);
        cheb_s[k][r][c * 4 + 0] = v.x; cheb_s[k][r][c * 4 + 1] = v.y;
        cheb_s[k][r][c * 4 + 2] = v.z; cheb_s[k][r][c * 4 + 3] = v.w;
      }

    for (int b = 0; b < NB; ++b) {
      __syncthreads();
#pragma unroll
      for (int p = 0; p < 4; ++p) {
        int r = r4 + p * 16;
        const float4 v = *(const float4*)(att + ((size_t)(b * NN + m0 + r)) * NN + n0 + c * 4);
        att_s[r][c * 4 + 0] = v.x; att_s[r][c * 4 + 1] = v.y;
        att_s[r][c * 4 + 2] = v.z; att_s[r][c * 4 + 3] = v.w;
      }
      __syncthreads();
      for (int k = 0; k < NK; ++k) {
#pragma unroll
        for (int p = 0; p < 8; ++p) {
          int e  = p * 256 + tid;
          int jn = e >> 5;
          int q  = e & 31;
          float f0 = att_s[2 * q][jn]     * cheb_s[k][2 * q][jn];
          float f1 = att_s[2 * q + 1][jn] * cheb_s[k][2 * q + 1][jn];
          unsigned int pk = (unsigned int)f2bf(f0) | ((unsigned int)f2bf(f1) << 16);
          size_t el = ((size_t)(b * NN + n0 + jn)) * KKC + k * NN + m0 + 2 * q;
          *(unsigned int*)(A2 + el) = pk;
        }
      }
    }
  }
}

// ---------------------------------------------------------------------------
// K4: out[b][n][q] = relu( A2[b] @ Y[b]^T ), 64x128 tile, BK=64 — r3-exact
// (measured floor of the decomposition: 53 µs; delivery saturates ~17-19
// TB/s from L3, all tile/schedule variants within the family are >= this).
// ---------------------------------------------------------------------------
__global__ __launch_bounds__(256) void k4_main(const unsigned short* __restrict__ A2,
                                               const unsigned short* __restrict__ Y,
                                               float* __restrict__ out) {
  __shared__ unsigned short Asl[64 * 64];    //  8 KB
  __shared__ unsigned short Bsl[128 * 64];   // 16 KB
  const int tid = threadIdx.x;
  const int w = tid >> 6, l = tid & 63;
  const int lrow = l & 15, lk = l >> 4;
  const int wm = w >> 1, wq = w & 1;

  const int lin = (blockIdx.x & 7) * 96 + (blockIdx.x >> 3);
  const int b   = lin / 96;
  const int rem = lin % 96;
  const int bn  = rem / 6;
  const int bq  = rem % 6;

  const unsigned short* Abase = A2 + ((size_t)(b * NN + bn * 64)) * KKC;
  const unsigned short* Bbase = Y  + ((size_t)(b * NQ + bq * 128)) * KKC;

  f32x4 acc[2][4] = {};

  for (int kt = 0; kt < KKC / 64; ++kt) {
    const int kb = kt * 64;
#pragma unroll
    for (int it = 0; it < 2; ++it) {
      const int idx = it * 256 + tid;
      const int r   = idx >> 3;
      const int c16 = (idx & 7) ^ (r & 7);
      gload_lds16(Abase + (size_t)r * KKC + kb + c16 * 8, Asl + (size_t)idx * 8);
    }
#pragma unroll
    for (int it = 0; it < 4; ++it) {
      const int idx = it * 256 + tid;
      const int r   = idx >> 3;
      const int c16 = (idx & 7) ^ (r & 7);
      gload_lds16(Bbase + (size_t)r * KKC + kb + c16 * 8, Bsl + (size_t)idx * 8);
    }
    __syncthreads();
#pragma unroll
    for (int kss = 0; kss < 2; ++kss) {
      bf16x8 af[2], bfr[4];
#pragma unroll
      for (int mi = 0; mi < 2; ++mi) {
        const int row = wm * 32 + mi * 16 + lrow;
        const int sw = (row * 128 + kss * 64 + lk * 16) ^ ((row & 7) << 4);
        af[mi] = *(const bf16x8*)((const char*)Asl + sw);
      }
#pragma unroll
      for (int nj = 0; nj < 4; ++nj) {
        const int row = wq * 64 + nj * 16 + lrow;
        const int sw = (row * 128 + kss * 64 + lk * 16) ^ ((row & 7) << 4);
        bfr[nj] = *(const bf16x8*)((const char*)Bsl + sw);
      }
#pragma unroll
      for (int mi = 0; mi < 2; ++mi)
#pragma unroll
        for (int nj = 0; nj < 4; ++nj)
          acc[mi][nj] = __builtin_amdgcn_mfma_f32_16x16x32_bf16(af[mi], bfr[nj], acc[mi][nj], 0, 0, 0);
    }
    __syncthreads();
  }

  const int nb0 = bn * 64 + wm * 32;
  const int qb0 = bq * 128 + wq * 64;
#pragma unroll
  for (int mi = 0; mi < 2; ++mi) {
#pragma unroll
    for (int nj = 0; nj < 4; ++nj) {
      const int q = qb0 + nj * 16 + lrow;
#pragma unroll
      for (int j = 0; j < 4; ++j) {
        const int n = nb0 + mi * 16 + lk * 4 + j;
        float v = acc[mi][nj][j];
        out[((size_t)(b * NN + n)) * NQ + q] = v > 0.f ? v : 0.f;
      }
    }
  }
}

// ---------------------------------------------------------------------------
extern "C" void kernel_launch(void* const* d_in, const int* in_sizes, int n_in,
                              void* d_out, int out_size, void* d_ws, size_t ws_size,
                              hipStream_t stream) {
  const float* x     = (const float*)d_in[0];   // (B,N,F,T)
  const float* att   = (const float*)d_in[1];   // (B,N,N)
  const float* cheb  = (const float*)d_in[2];   // (K,N,N)
  const float* theta = (const float*)d_in[3];   // (K,F,O)
  float* out = (float*)d_out;

  char* ws = (char*)d_ws;
  unsigned short* A2  = (unsigned short*)(ws);                 // 50,331,648 B
  unsigned short* Y   = (unsigned short*)(ws + 50331648);      // 37,748,736 B
  unsigned short* thT = (unsigned short*)(ws + 88080384);      //     24,576 B

  k0_thetaT<<<48, 256, 0, stream>>>(theta, thT);
  k123<<<768, 256, 0, stream>>>(x, thT, Y, cheb, att, A2);
  k4_main<<<768, 256, 0, stream>>>(A2, Y, out);
}

// Round 14
// 94.053 us; speedup vs baseline: 1.1664x; 1.0061x over previous
//
#include <hip/hip_runtime.h>
#include <stdint.h>

#define NB 8
#define NN 1024
#define NF 64
#define NT 12
#define NK 3
#define NO 64
#define NQ 768      // O*T
#define KKC 3072    // NK*NN contraction

typedef __attribute__((ext_vector_type(8))) short bf16x8;
typedef __attribute__((ext_vector_type(4))) float f32x4;

typedef const unsigned int __attribute__((address_space(1)))* gas1_t;
typedef unsigned int __attribute__((address_space(3)))* las3_t;

__device__ __forceinline__ void gload_lds16(const void* g, void* l) {
  __builtin_amdgcn_global_load_lds((gas1_t)g, (las3_t)l, 16, 0, 0);
}

__device__ __forceinline__ unsigned short f2bf(float f) {
  union { float f; unsigned int u; } v; v.f = f;
  unsigned int u = v.u;
  unsigned int r = (u + 0x7FFFu + ((u >> 16) & 1u)) >> 16;
  return (unsigned short)r;
}

// ---------------------------------------------------------------------------
// K0: thetaT[k][o][f] = bf16(theta[k][f][o])
// ---------------------------------------------------------------------------
__global__ void k0_thetaT(const float* __restrict__ theta, unsigned short* __restrict__ thT) {
  int i = blockIdx.x * 256 + threadIdx.x;
  if (i >= NK * NO * NF) return;
  int f = i & 63, o = (i >> 6) & 63, k = i >> 12;
  thT[i] = f2bf(theta[(k * NF + f) * NO + o]);
}

// ---------------------------------------------------------------------------
// K123 (fused, occupancy-fixed): 2560 blocks, whole-block role split.
//   blocks [0,512):    k23 role — Y[b][(o,t)][k*1024+m] = sum_f x*theta
//     (no Ts LDS copy: theta B-fragments read from global, L1/L2-resident;
//      k-outer loop, af hoisted; LDS = Xs 24 KB)
//   blocks [512,2560): k1 role — A2[b][n][k*1024+m] = bf16(cheb*att),
//     r1-style per-b tiles (2048 blocks), single-k cheb staging, 33.3 KB.
// Fused LDS = 33.3 KB -> 4 blocks/CU, 16 waves (was 2 blocks/8 waves).
// ---------------------------------------------------------------------------
__global__ __launch_bounds__(256) void k123(const float* __restrict__ x,
                                            const unsigned short* __restrict__ thT,
                                            unsigned short* __restrict__ Y,
                                            const float* __restrict__ cheb,
                                            const float* __restrict__ att,
                                            unsigned short* __restrict__ A2) {
  __shared__ alignas(16) char smem[33280];
  const int bid = blockIdx.x;
  const int tid = threadIdx.x;

  if (bid < 512) {
    // ---------------- k23 role: build Y ----------------
    unsigned short* Xs = (unsigned short*)smem;            // 24 KB, t-plane 2048 B
    const int mc = bid & 63;
    const int b  = bid >> 6;
    const int w = tid >> 6, l = tid & 63;
    const int lrow = l & 15, lk = l >> 4;

    const float* xb = x + ((size_t)(b * NN + mc * 16)) * (NF * NT);
#pragma unroll
    for (int u0 = 0; u0 < 2; ++u0) {
      const int u  = u0 * 256 + tid;       // 0..511
      const int m  = u >> 5;               // 0..15
      const int fp = u & 31;               // f-pair
      const float* src = xb + ((size_t)m * NF + fp * 2) * NT;
      float v[24];
#pragma unroll
      for (int i = 0; i < 6; ++i)
        *(float4*)(v + i * 4) = *(const float4*)(src + i * 4);
#pragma unroll
      for (int t = 0; t < 12; ++t) {
        unsigned int pk = (unsigned int)f2bf(v[t]) | ((unsigned int)f2bf(v[t + 12]) << 16);
        const int byte = (t * 2048 + m * 128 + fp * 4) ^ ((m & 7) << 4);
        *(unsigned int*)((char*)Xs + byte) = pk;
      }
    }
    __syncthreads();

    // hoist A-fragments for this wave's 3 t's (Xs never overwritten)
    bf16x8 af[3][2];
#pragma unroll
    for (int ti = 0; ti < 3; ++ti) {
      const int t = w * 3 + ti;
#pragma unroll
      for (int kss = 0; kss < 2; ++kss) {
        const int byte = (t * 2048 + lrow * 128 + kss * 64 + lk * 16) ^ ((lrow & 7) << 4);
        af[ti][kss] = *(const bf16x8*)((const char*)Xs + byte);
      }
    }

    for (int k = 0; k < NK; ++k) {
      // theta B-fragments from global (24 KB table, L1/L2-hot, same for all blocks)
      bf16x8 bb[2][4];
#pragma unroll
      for (int kss = 0; kss < 2; ++kss)
#pragma unroll
        for (int oj = 0; oj < 4; ++oj)
          bb[kss][oj] = *(const bf16x8*)(thT + (size_t)(k * NO + oj * 16 + lrow) * NF + kss * 32 + lk * 8);
#pragma unroll
      for (int ti = 0; ti < 3; ++ti) {
        const int t = w * 3 + ti;
        f32x4 acc[4] = {};
#pragma unroll
        for (int kss = 0; kss < 2; ++kss)
#pragma unroll
          for (int oj = 0; oj < 4; ++oj)
            acc[oj] = __builtin_amdgcn_mfma_f32_16x16x32_bf16(af[ti][kss], bb[kss][oj], acc[oj], 0, 0, 0);
#pragma unroll
        for (int oj = 0; oj < 4; ++oj) {
          const int o  = oj * 16 + lrow;
          const int mg = mc * 16 + lk * 4;
          uint2 u;
          u.x = (unsigned int)f2bf(acc[oj][0]) | ((unsigned int)f2bf(acc[oj][1]) << 16);
          u.y = (unsigned int)f2bf(acc[oj][2]) | ((unsigned int)f2bf(acc[oj][3]) << 16);
          size_t el = ((size_t)(b * NQ + o * NT + t)) * KKC + k * NN + mg;
          *(uint2*)(void*)(Y + el) = u;
        }
      }
    }
  } else {
    // ---------------- k1 role: build A2 (r1-style, per-b tiles) ----------------
    float (*att_s)[65]  = (float(*)[65])smem;                 // 16640 B
    float (*cheb_s)[65] = (float(*)[65])(smem + 16640);       // 16640 B
    const int bid2 = bid - 512;          // 0..2047
    const int n0 = (bid2 & 15) * 64;
    const int m0 = ((bid2 >> 4) & 15) * 64;
    const int b  = bid2 >> 8;
    const int r4 = tid >> 4;
    const int c  = tid & 15;

#pragma unroll
    for (int p = 0; p < 4; ++p) {
      int r = r4 + p * 16;
      const float4 v = *(const float4*)(att + ((size_t)(b * NN + m0 + r)) * NN + n0 + c * 4);
      att_s[r][c * 4 + 0] = v.x; att_s[r][c * 4 + 1] = v.y;
      att_s[r][c * 4 + 2] = v.z; att_s[r][c * 4 + 3] = v.w;
    }
    for (int k = 0; k < NK; ++k) {
      if (k) __syncthreads();            // prev k's cheb_s reads done
#pragma unroll
      for (int p = 0; p < 4; ++p) {
        int r = r4 + p * 16;
        const float4 v = *(const float4*)(cheb + ((size_t)(k * NN + m0 + r)) * NN + n0 + c * 4);
        cheb_s[r][c * 4 + 0] = v.x; cheb_s[r][c * 4 + 1] = v.y;
        cheb_s[r][c * 4 + 2] = v.z; cheb_s[r][c * 4 + 3] = v.w;
      }
      __syncthreads();                   // cheb (and att on k=0) ready
#pragma unroll
      for (int p = 0; p < 8; ++p) {
        int e  = p * 256 + tid;
        int jn = e >> 5;
        int q  = e & 31;
        float f0 = att_s[2 * q][jn]     * cheb_s[2 * q][jn];
        float f1 = att_s[2 * q + 1][jn] * cheb_s[2 * q + 1][jn];
        unsigned int pk = (unsigned int)f2bf(f0) | ((unsigned int)f2bf(f1) << 16);
        size_t el = ((size_t)(b * NN + n0 + jn)) * KKC + k * NN + m0 + 2 * q;
        *(unsigned int*)(A2 + el) = pk;
      }
    }
  }
}

// ---------------------------------------------------------------------------
// K4: out[b][n][q] = relu( A2[b] @ Y[b]^T ), 64x128 tile, BK=64 — r3-exact
// (measured decomposition floor: ~53 µs = 906 MB staged / ~17 TB/s L3
// delivery wall; all tile/schedule variants in the family measured >= this).
// ---------------------------------------------------------------------------
__global__ __launch_bounds__(256) void k4_main(const unsigned short* __restrict__ A2,
                                               const unsigned short* __restrict__ Y,
                                               float* __restrict__ out) {
  __shared__ unsigned short Asl[64 * 64];    //  8 KB
  __shared__ unsigned short Bsl[128 * 64];   // 16 KB
  const int tid = threadIdx.x;
  const int w = tid >> 6, l = tid & 63;
  const int lrow = l & 15, lk = l >> 4;
  const int wm = w >> 1, wq = w & 1;

  const int lin = (blockIdx.x & 7) * 96 + (blockIdx.x >> 3);
  const int b   = lin / 96;
  const int rem = lin % 96;
  const int bn  = rem / 6;
  const int bq  = rem % 6;

  const unsigned short* Abase = A2 + ((size_t)(b * NN + bn * 64)) * KKC;
  const unsigned short* Bbase = Y  + ((size_t)(b * NQ + bq * 128)) * KKC;

  f32x4 acc[2][4] = {};

  for (int kt = 0; kt < KKC / 64; ++kt) {
    const int kb = kt * 64;
#pragma unroll
    for (int it = 0; it < 2; ++it) {
      const int idx = it * 256 + tid;
      const int r   = idx >> 3;
      const int c16 = (idx & 7) ^ (r & 7);
      gload_lds16(Abase + (size_t)r * KKC + kb + c16 * 8, Asl + (size_t)idx * 8);
    }
#pragma unroll
    for (int it = 0; it < 4; ++it) {
      const int idx = it * 256 + tid;
      const int r   = idx >> 3;
      const int c16 = (idx & 7) ^ (r & 7);
      gload_lds16(Bbase + (size_t)r * KKC + kb + c16 * 8, Bsl + (size_t)idx * 8);
    }
    __syncthreads();
#pragma unroll
    for (int kss = 0; kss < 2; ++kss) {
      bf16x8 af[2], bfr[4];
#pragma unroll
      for (int mi = 0; mi < 2; ++mi) {
        const int row = wm * 32 + mi * 16 + lrow;
        const int sw = (row * 128 + kss * 64 + lk * 16) ^ ((row & 7) << 4);
        af[mi] = *(const bf16x8*)((const char*)Asl + sw);
      }
#pragma unroll
      for (int nj = 0; nj < 4; ++nj) {
        const int row = wq * 64 + nj * 16 + lrow;
        const int sw = (row * 128 + kss * 64 + lk * 16) ^ ((row & 7) << 4);
        bfr[nj] = *(const bf16x8*)((const char*)Bsl + sw);
      }
#pragma unroll
      for (int mi = 0; mi < 2; ++mi)
#pragma unroll
        for (int nj = 0; nj < 4; ++nj)
          acc[mi][nj] = __builtin_amdgcn_mfma_f32_16x16x32_bf16(af[mi], bfr[nj], acc[mi][nj], 0, 0, 0);
    }
    __syncthreads();
  }

  const int nb0 = bn * 64 + wm * 32;
  const int qb0 = bq * 128 + wq * 64;
#pragma unroll
  for (int mi = 0; mi < 2; ++mi) {
#pragma unroll
    for (int nj = 0; nj < 4; ++nj) {
      const int q = qb0 + nj * 16 + lrow;
#pragma unroll
      for (int j = 0; j < 4; ++j) {
        const int n = nb0 + mi * 16 + lk * 4 + j;
        float v = acc[mi][nj][j];
        out[((size_t)(b * NN + n)) * NQ + q] = v > 0.f ? v : 0.f;
      }
    }
  }
}

// ---------------------------------------------------------------------------
extern "C" void kernel_launch(void* const* d_in, const int* in_sizes, int n_in,
                              void* d_out, int out_size, void* d_ws, size_t ws_size,
                              hipStream_t stream) {
  const float* x     = (const float*)d_in[0];   // (B,N,F,T)
  const float* att   = (const float*)d_in[1];   // (B,N,N)
  const float* cheb  = (const float*)d_in[2];   // (K,N,N)
  const float* theta = (const float*)d_in[3];   // (K,F,O)
  float* out = (float*)d_out;

  char* ws = (char*)d_ws;
  unsigned short* A2  = (unsigned short*)(ws);                 // 50,331,648 B
  unsigned short* Y   = (unsigned short*)(ws + 50331648);      // 37,748,736 B
  unsigned short* thT = (unsigned short*)(ws + 88080384);      //     24,576 B

  k0_thetaT<<<48, 256, 0, stream>>>(theta, thT);
  k123<<<2560, 256, 0, stream>>>(x, thT, Y, cheb, att, A2);
  k4_main<<<768, 256, 0, stream>>>(A2, Y, out);
}